// Round 11
// baseline (65.211 us; speedup 1.0000x reference)
//
#include <hip/hip_runtime.h>

#define BATCH 8
#define CIN 64
#define H 128
#define W 128
#define OCH 64
#define HW (H*W)
#define OFFCH 18

using f16x8 = __attribute__((ext_vector_type(8))) _Float16;
using f32x4 = __attribute__((ext_vector_type(4))) float;

static __device__ __forceinline__ int iclamp(int v, int lo, int hi) {
    return v < lo ? lo : (v > hi ? hi : v);
}
static __device__ __forceinline__ f16x8 splat8(_Float16 v) {
    return (f16x8){v, v, v, v, v, v, v, v};
}
static __device__ __forceinline__ unsigned packh2(float a, float b) {
    union { _Float16 h[2]; unsigned u; } pk;
    pk.h[0] = (_Float16)a; pk.h[1] = (_Float16)b;
    return pk.u;
}

// ---------------- transpose x [B][C][H][W] f32 -> xt [B][H][W][C] f16 ----------------
__global__ __launch_bounds__(256) void transpose_x_kernel(
    const float* __restrict__ x, _Float16* __restrict__ xt)
{
    __shared__ float ls[CIN][129];
    int bid = blockIdx.x;          // B*H = 1024
    int b = bid >> 7, y = bid & 127;
    int t = threadIdx.x;

    const float* xb = x + (size_t)b * CIN * HW + (size_t)y * W;
    #pragma unroll 4
    for (int i = 0; i < 32; ++i) {
        int c = i * 2 + (t >> 7);
        ls[c][t & 127] = xb[(size_t)c * HW + (t & 127)];
    }
    __syncthreads();

    _Float16* xo = xt + (size_t)(b * H + y) * W * CIN;
    #pragma unroll 4
    for (int i = 0; i < 16; ++i) {
        int px = i * 8 + (t >> 5);
        int c  = (t & 31) * 2;
        _Float16 a0 = (_Float16)ls[c][px];
        _Float16 a1 = (_Float16)ls[c + 1][px];
        union { _Float16 h[2]; unsigned int u; } pk;
        pk.h[0] = a0; pk.h[1] = a1;
        *(unsigned int*)&xo[(size_t)px * CIN + c] = pk.u;
    }
}

// ---------------- prep w_deform -> f16 MFMA A-frag order ----------------
__global__ __launch_bounds__(256) void prep_wdf_kernel(
    const float* __restrict__ w, _Float16* __restrict__ wdf)
{
    int i = blockIdx.x * 256 + threadIdx.x;   // 9*2*4*64*8 = 36864
    if (i >= 9 * 2 * 4 * 64 * 8) return;
    int j    = i & 7;
    int lane = (i >> 3) & 63;
    int mt   = (i >> 9) & 3;
    int cs   = (i >> 11) & 1;
    int tap  = i >> 12;
    int oc = mt * 16 + (lane & 15);
    int c  = cs * 32 + (lane >> 4) * 8 + j;
    wdf[i] = (_Float16)w[(oc * CIN + c) * 9 + tap];
}

// ---------------- prep w_offset -> f16 MFMA A-frag order (M padded 18->32) ----------------
__global__ __launch_bounds__(256) void prep_wof_kernel(
    const float* __restrict__ w, _Float16* __restrict__ wof)
{
    int i = blockIdx.x * 256 + threadIdx.x;   // 9*2*2*64*8 = 18432
    if (i >= 9 * 2 * 2 * 64 * 8) return;
    int j    = i & 7;
    int lane = (i >> 3) & 63;
    int mt   = (i >> 9) & 1;
    int cs   = (i >> 10) & 1;
    int tap  = i >> 11;
    int oc = mt * 16 + (lane & 15);
    int c  = cs * 32 + (lane >> 4) * 8 + j;
    wof[i] = (oc < OFFCH) ? (_Float16)w[(oc * CIN + c) * 9 + tap] : (_Float16)0.f;
}

// ---------------- fused offset-conv + deformable conv, record-based ----------------
// Grid 512 = (b, ypair); 1024 threads = 16 waves; wave w: row y+(w>>3), px (w&7)*16+l15.
// Rows [y-2, y+3] staged in LDS (swizzled). Per-tap __syncthreads() keeps the 16 waves'
// weight-stream reads in lockstep so L1 serves 15/16 of the wof/wdf traffic (L2-BW fix).
__global__ __launch_bounds__(1024, 4) void fused_deform_kernel(
    const _Float16* __restrict__ xt, const f16x8* __restrict__ wof,
    const f16x8* __restrict__ wdf, const float* __restrict__ bias,
    float* __restrict__ out)
{
    __shared__ _Float16 band[6 * 128 * CIN];       // 96 KB; chunk-swizzled per pixel
    __shared__ uint4 recs[16 * 16 * 9];            // 36 KB: per (wave,px,tap) record
    __shared__ unsigned int offs_f[16 * 16 * 9];   // 9 KB: f16 offset pairs (fallback only)

    int bid  = blockIdx.x;           // 512
    int b    = bid & 7;              // one batch per XCD
    int y    = (bid >> 3) * 2;       // block covers rows y, y+1
    int tid  = threadIdx.x;
    int lane = tid & 63;
    int wave = tid >> 6;             // 0..15
    int l15  = lane & 15;
    int lk   = lane >> 4;
    int yo   = y + (wave >> 3);      // this wave's output row
    int p    = (wave & 7) * 16 + l15;

    int ylo = y - 2 < 0 ? 0 : y - 2;
    int yhi = y + 3 > H - 1 ? H - 1 : y + 3;
    int nrm1 = yhi - ylo;

    const _Float16* xb = xt + (size_t)b * HW * CIN;

    // ---- stage band rows [ylo..yhi] -> LDS; thread = (px, jl) ----
    {
        int spx = tid >> 3;
        int sjl = tid & 7;
        int sjp = sjl ^ (spx & 7);
        #pragma unroll
        for (int r = 0; r < 6; ++r) {
            int gy = ylo + r;
            if (gy > yhi) break;
            *(f16x8*)&band[(((size_t)r * 128 + spx) * 8 + sjp) * 8] =
                *(const f16x8*)&xb[((size_t)gy * W + spx) * CIN + sjl * 8];
        }
    }
    __syncthreads();

    // ======== phase 1: offset conv (M=32 padded, N=16/wave, K=576), B from band ========
    f32x4 oacc[2];
    oacc[0] = (f32x4){0.f, 0.f, 0.f, 0.f};
    oacc[1] = (f32x4){0.f, 0.f, 0.f, 0.f};

    #pragma unroll
    for (int tap = 0; tap < 9; ++tap) {
        __syncthreads();   // lockstep wof stream across 16 waves -> L1 reuse
        int ky = tap / 3, kx = tap - 3 * ky;
        int yy = yo - 1 + ky;
        int pos = p - 1 + kx;
        bool inb = (yy >= 0 && yy < H && pos >= 0 && pos < W);
        int ry = yy - ylo;
        #pragma unroll
        for (int cs = 0; cs < 2; ++cs) {
            const f16x8* wf = wof + (size_t)((tap * 2 + cs) * 2) * 64 + lane;
            f16x8 a0 = wf[0];
            f16x8 a1 = wf[64];
            f16x8 bfrag = splat8((_Float16)0.f);
            if (inb) {
                int jp = (cs * 4 + lk) ^ (pos & 7);
                bfrag = *(const f16x8*)&band[(((size_t)ry * 128 + pos) * 8 + jp) * 8];
            }
            oacc[0] = __builtin_amdgcn_mfma_f32_16x16x32_f16(a0, bfrag, oacc[0], 0, 0, 0);
            oacc[1] = __builtin_amdgcn_mfma_f32_16x16x32_f16(a1, bfrag, oacc[1], 0, 0, 0);
        }
    }

    // ======== record build: lane (l15,lk) owns taps {2lk, 2lk+1} (+8 for lk==0) ========
    int rbase = (wave * 16 + l15) * 9;
    auto build = [&](int tap, float offy, float offx) {
        int ky = tap / 3, kx = tap - 3 * ky;
        float py  = (float)(yo - 1 + ky) + offy;
        float pxf = (float)(p  - 1 + kx) + offx;
        float y0f = floorf(py), x0f = floorf(pxf);
        float fy = py - y0f, fx = pxf - x0f;
        int y0 = (int)y0f, x0 = (int)x0f;
        int y1 = y0 + 1, x1 = x0 + 1;
        float m00 = (1.f - fy) * (1.f - fx);
        float m01 = (1.f - fy) * fx;
        float m10 = fy * (1.f - fx);
        float m11 = fy * fx;
        if (y0 < 0 || y0 >= H) { m00 = 0.f; m01 = 0.f; }
        if (y1 < 0 || y1 >= H) { m10 = 0.f; m11 = 0.f; }
        if (x0 < 0 || x0 >= W) { m00 = 0.f; m10 = 0.f; }
        if (x1 < 0 || x1 >= W) { m01 = 0.f; m11 = 0.f; }
        int y0c = iclamp(y0, 0, H - 1), y1c = iclamp(y1, 0, H - 1);
        int x0c = iclamp(x0, 0, W - 1), x1c = iclamp(x1, 0, W - 1);
        int ry0 = y0c - ylo, ry1 = y1c - ylo;
        unsigned o0 = (ry0 < 0 || ry0 > nrm1) ? 0x8000u : 0u;
        unsigned o1 = (ry1 < 0 || ry1 > nrm1) ? 0x8000u : 0u;
        int r0 = iclamp(ry0, 0, 5), r1 = iclamp(ry1, 0, 5);
        unsigned f0 = (unsigned)(((r0 * 128 + x0c) << 3) | (x0c & 7)) | o0;
        unsigned f1 = (unsigned)(((r0 * 128 + x1c) << 3) | (x1c & 7)) | o0;
        unsigned f2 = (unsigned)(((r1 * 128 + x0c) << 3) | (x0c & 7)) | o1;
        unsigned f3 = (unsigned)(((r1 * 128 + x1c) << 3) | (x1c & 7)) | o1;
        uint4 rc;
        rc.x = packh2(m00, m01);
        rc.y = packh2(m10, m11);
        rc.z = f0 | (f1 << 16);
        rc.w = f2 | (f3 << 16);
        recs[rbase + tap] = rc;
        offs_f[rbase + tap] = packh2(offy, offx);
    };
    build(2 * lk,     oacc[0][0], oacc[0][1]);
    build(2 * lk + 1, oacc[0][2], oacc[0][3]);
    if (lk == 0) build(8, oacc[1][0], oacc[1][1]);
    // no barrier needed for records themselves: produced/consumed by the SAME wave

    // ======== phase 2: deformable conv (M=64, N=16/wave, K=576) ========
    f32x4 acc[4];
    #pragma unroll
    for (int mt = 0; mt < 4; ++mt) acc[mt] = (f32x4){0.f, 0.f, 0.f, 0.f};

    const char* bb = (const char*)band;

    #pragma unroll
    for (int tap = 0; tap < 9; ++tap) {
        __syncthreads();   // lockstep wdf stream across 16 waves -> L1 reuse
        uint4 rc = recs[rbase + tap];
        union { unsigned u; _Float16 h[2]; } mA, mB;
        mA.u = rc.x; mB.u = rc.y;
        _Float16 h00 = mA.h[0], h01 = mA.h[1], h10 = mB.h[0], h11 = mB.h[1];
        int f0 = rc.z & 0xffff, f1 = rc.z >> 16;
        int f2 = rc.w & 0xffff, f3 = rc.w >> 16;
        bool fall = ((rc.z | rc.w) & 0x8000u) != 0;
        // byte addresses into band for cs=0; cs=1 is ^64 (jl -> jl+4 => jp -> jp^4)
        int a00 = (((f0 >> 3) & 1023) << 7) + ((lk ^ (f0 & 7)) << 4);
        int a01 = (((f1 >> 3) & 1023) << 7) + ((lk ^ (f1 & 7)) << 4);
        int a10 = (((f2 >> 3) & 1023) << 7) + ((lk ^ (f2 & 7)) << 4);
        int a11 = (((f3 >> 3) & 1023) << 7) + ((lk ^ (f3 & 7)) << 4);

        f16x8 bf0, bf1;
        {
            f16x8 g00 = *(const f16x8*)(bb + a00);
            f16x8 g01 = *(const f16x8*)(bb + a01);
            f16x8 g10 = *(const f16x8*)(bb + a10);
            f16x8 g11 = *(const f16x8*)(bb + a11);
            bf0 = g00 * splat8(h00) + g01 * splat8(h01)
                + g10 * splat8(h10) + g11 * splat8(h11);
            f16x8 k00 = *(const f16x8*)(bb + (a00 ^ 64));
            f16x8 k01 = *(const f16x8*)(bb + (a01 ^ 64));
            f16x8 k10 = *(const f16x8*)(bb + (a10 ^ 64));
            f16x8 k11 = *(const f16x8*)(bb + (a11 ^ 64));
            bf1 = k00 * splat8(h00) + k01 * splat8(h01)
                + k10 * splat8(h10) + k11 * splat8(h11);
        }
        if (fall) {   // rare: corner row outside staged band -> full recompute from global
            union { unsigned u; _Float16 h[2]; } of;
            of.u = offs_f[rbase + tap];
            float offy = (float)of.h[0], offx = (float)of.h[1];
            int ky = tap / 3, kx = tap - 3 * ky;
            float py  = (float)(yo - 1 + ky) + offy;
            float pxf = (float)(p  - 1 + kx) + offx;
            float y0f = floorf(py), x0f = floorf(pxf);
            float fy = py - y0f, fx = pxf - x0f;
            int y0 = (int)y0f, x0 = (int)x0f;
            int y1 = y0 + 1, x1 = x0 + 1;
            float n00 = (1.f - fy) * (1.f - fx);
            float n01 = (1.f - fy) * fx;
            float n10 = fy * (1.f - fx);
            float n11 = fy * fx;
            if (y0 < 0 || y0 >= H) { n00 = 0.f; n01 = 0.f; }
            if (y1 < 0 || y1 >= H) { n10 = 0.f; n11 = 0.f; }
            if (x0 < 0 || x0 >= W) { n00 = 0.f; n10 = 0.f; }
            if (x1 < 0 || x1 >= W) { n01 = 0.f; n11 = 0.f; }
            int y0c = iclamp(y0, 0, H - 1), y1c = iclamp(y1, 0, H - 1);
            int x0c = iclamp(x0, 0, W - 1), x1c = iclamp(x1, 0, W - 1);
            _Float16 q00 = (_Float16)n00, q01 = (_Float16)n01;
            _Float16 q10 = (_Float16)n10, q11 = (_Float16)n11;
            size_t i00 = ((size_t)y0c * W + x0c) * CIN, i01 = ((size_t)y0c * W + x1c) * CIN;
            size_t i10 = ((size_t)y1c * W + x0c) * CIN, i11 = ((size_t)y1c * W + x1c) * CIN;
            int c0 = lk * 8;
            bf0 = (*(const f16x8*)&xb[i00 + c0]) * splat8(q00)
                + (*(const f16x8*)&xb[i01 + c0]) * splat8(q01)
                + (*(const f16x8*)&xb[i10 + c0]) * splat8(q10)
                + (*(const f16x8*)&xb[i11 + c0]) * splat8(q11);
            int c1 = 32 + lk * 8;
            bf1 = (*(const f16x8*)&xb[i00 + c1]) * splat8(q00)
                + (*(const f16x8*)&xb[i01 + c1]) * splat8(q01)
                + (*(const f16x8*)&xb[i10 + c1]) * splat8(q10)
                + (*(const f16x8*)&xb[i11 + c1]) * splat8(q11);
        }

        #pragma unroll
        for (int cs = 0; cs < 2; ++cs) {
            f16x8 bfrag = cs ? bf1 : bf0;
            const f16x8* wf = wdf + (size_t)((tap * 2 + cs) * 4) * 64 + lane;
            #pragma unroll
            for (int mt = 0; mt < 4; ++mt)
                acc[mt] = __builtin_amdgcn_mfma_f32_16x16x32_f16(
                    wf[mt * 64], bfrag, acc[mt], 0, 0, 0);
        }
    }

    #pragma unroll
    for (int mt = 0; mt < 4; ++mt) {
        #pragma unroll
        for (int r = 0; r < 4; ++r) {
            int oc = mt * 16 + lk * 4 + r;
            out[((size_t)b * OCH + oc) * HW + (size_t)yo * W + p] = acc[mt][r] + bias[oc];
        }
    }
}

extern "C" void kernel_launch(void* const* d_in, const int* in_sizes, int n_in,
                              void* d_out, int out_size, void* d_ws, size_t ws_size,
                              hipStream_t stream) {
    const float* x     = (const float*)d_in[0];
    const float* w_off = (const float*)d_in[1];
    const float* w_def = (const float*)d_in[2];
    const float* b_def = (const float*)d_in[3];
    float* out = (float*)d_out;

    _Float16* xt  = (_Float16*)d_ws;                 // 8.4M f16 (16.8 MB)
    _Float16* wdf = xt + (size_t)BATCH * HW * CIN;   // 36,864 f16
    _Float16* wof = wdf + 36864;                     // 18,432 f16

    transpose_x_kernel<<<BATCH * H, 256, 0, stream>>>(x, xt);
    prep_wdf_kernel<<<(36864 + 255) / 256, 256, 0, stream>>>(w_def, wdf);
    prep_wof_kernel<<<(18432 + 255) / 256, 256, 0, stream>>>(w_off, wof);
    fused_deform_kernel<<<BATCH * H / 2, 1024, 0, stream>>>(
        xt, (const f16x8*)wof, (const f16x8*)wdf, b_def, out);
}

// Round 12
// 55.120 us; speedup vs baseline: 1.1831x; 1.1831x over previous
//
#include <hip/hip_runtime.h>

#define BATCH 8
#define CIN 64
#define H 128
#define W 128
#define OCH 64
#define HW (H*W)
#define OFFCH 18

using f16x8 = __attribute__((ext_vector_type(8))) _Float16;
using f32x4 = __attribute__((ext_vector_type(4))) float;

static __device__ __forceinline__ int iclamp(int v, int lo, int hi) {
    return v < lo ? lo : (v > hi ? hi : v);
}
static __device__ __forceinline__ f16x8 splat8(_Float16 v) {
    return (f16x8){v, v, v, v, v, v, v, v};
}
static __device__ __forceinline__ unsigned packh2(float a, float b) {
    union { _Float16 h[2]; unsigned u; } pk;
    pk.h[0] = (_Float16)a; pk.h[1] = (_Float16)b;
    return pk.u;
}

// ---------------- transpose x [B][C][H][W] f32 -> xt [B][H][W][C] f16 ----------------
__global__ __launch_bounds__(256) void transpose_x_kernel(
    const float* __restrict__ x, _Float16* __restrict__ xt)
{
    __shared__ float ls[CIN][129];
    int bid = blockIdx.x;          // B*H = 1024
    int b = bid >> 7, y = bid & 127;
    int t = threadIdx.x;

    const float* xb = x + (size_t)b * CIN * HW + (size_t)y * W;
    #pragma unroll 4
    for (int i = 0; i < 32; ++i) {
        int c = i * 2 + (t >> 7);
        ls[c][t & 127] = xb[(size_t)c * HW + (t & 127)];
    }
    __syncthreads();

    _Float16* xo = xt + (size_t)(b * H + y) * W * CIN;
    #pragma unroll 4
    for (int i = 0; i < 16; ++i) {
        int px = i * 8 + (t >> 5);
        int c  = (t & 31) * 2;
        _Float16 a0 = (_Float16)ls[c][px];
        _Float16 a1 = (_Float16)ls[c + 1][px];
        union { _Float16 h[2]; unsigned int u; } pk;
        pk.h[0] = a0; pk.h[1] = a1;
        *(unsigned int*)&xo[(size_t)px * CIN + c] = pk.u;
    }
}

// ---------------- prep w_deform -> f16 MFMA A-frag order ----------------
__global__ __launch_bounds__(256) void prep_wdf_kernel(
    const float* __restrict__ w, _Float16* __restrict__ wdf)
{
    int i = blockIdx.x * 256 + threadIdx.x;   // 9*2*4*64*8 = 36864
    if (i >= 9 * 2 * 4 * 64 * 8) return;
    int j    = i & 7;
    int lane = (i >> 3) & 63;
    int mt   = (i >> 9) & 3;
    int cs   = (i >> 11) & 1;
    int tap  = i >> 12;
    int oc = mt * 16 + (lane & 15);
    int c  = cs * 32 + (lane >> 4) * 8 + j;
    wdf[i] = (_Float16)w[(oc * CIN + c) * 9 + tap];
}

// ---------------- prep w_offset -> f16 MFMA A-frag order (M padded 18->32) ----------------
__global__ __launch_bounds__(256) void prep_wof_kernel(
    const float* __restrict__ w, _Float16* __restrict__ wof)
{
    int i = blockIdx.x * 256 + threadIdx.x;   // 9*2*2*64*8 = 18432
    if (i >= 9 * 2 * 2 * 64 * 8) return;
    int j    = i & 7;
    int lane = (i >> 3) & 63;
    int mt   = (i >> 9) & 1;
    int cs   = (i >> 10) & 1;
    int tap  = i >> 11;
    int oc = mt * 16 + (lane & 15);
    int c  = cs * 32 + (lane >> 4) * 8 + j;
    wof[i] = (oc < OFFCH) ? (_Float16)w[(oc * CIN + c) * 9 + tap] : (_Float16)0.f;
}

// ---------------- fused offset-conv + deformable conv, N=32/wave ----------------
// Grid 512 = (b, ypair); 512 threads = 8 waves; wave w: row y+(w>>2), px (w&3)*32 + nt*16 + l15.
// Each A-fragment feeds TWO B-frags (nt=0,1) -> weight traffic per pixel halved vs N=16.
// Rows [y-2, y+3] staged in LDS (swizzled). Records intra-wave -> no phase barrier.
__global__ __launch_bounds__(512, 2) void fused_deform_kernel(
    const _Float16* __restrict__ xt, const f16x8* __restrict__ wof,
    const f16x8* __restrict__ wdf, const float* __restrict__ bias,
    float* __restrict__ out)
{
    __shared__ _Float16 band[6 * 128 * CIN];       // 96 KB; chunk-swizzled per pixel
    __shared__ uint4 recs[2 * 128 * 9];            // 36 KB: per (row,px,tap) record
    __shared__ unsigned int offs_f[2 * 128 * 9];   // 9 KB: f16 offset pairs (fallback only)

    int bid  = blockIdx.x;           // 512
    int b    = bid & 7;              // one batch per XCD
    int y    = (bid >> 3) * 2;       // block covers rows y, y+1
    int tid  = threadIdx.x;
    int lane = tid & 63;
    int wave = tid >> 6;             // 0..7
    int l15  = lane & 15;
    int lk   = lane >> 4;
    int rw   = wave >> 2;            // wave's output row (0/1)
    int yo   = y + rw;
    int pxbase = (wave & 3) * 32;
    int p0   = pxbase + l15;         // nt=0 pixel
    int p1   = p0 + 16;              // nt=1 pixel

    int ylo = y - 2 < 0 ? 0 : y - 2;
    int yhi = y + 3 > H - 1 ? H - 1 : y + 3;
    int nrm1 = yhi - ylo;

    const _Float16* xb = xt + (size_t)b * HW * CIN;

    // ---- stage band rows [ylo..yhi] -> LDS; 1024 chunks/row, 512 threads -> 2 each ----
    {
        #pragma unroll
        for (int r = 0; r < 6; ++r) {
            int gy = ylo + r;
            if (gy > yhi) break;
            #pragma unroll
            for (int i = 0; i < 2; ++i) {
                int linear = i * 512 + tid;
                int spx = linear >> 3;
                int sjl = linear & 7;
                int sjp = sjl ^ (spx & 7);
                *(f16x8*)&band[(((size_t)r * 128 + spx) * 8 + sjp) * 8] =
                    *(const f16x8*)&xb[((size_t)gy * W + spx) * CIN + sjl * 8];
            }
        }
    }
    __syncthreads();

    // ======== phase 1: offset conv (M=32 padded, N=32/wave, K=576), B from band ========
    f32x4 oacc[2][2];   // [mt][nt]
    #pragma unroll
    for (int mt = 0; mt < 2; ++mt)
        #pragma unroll
        for (int nt = 0; nt < 2; ++nt) oacc[mt][nt] = (f32x4){0.f, 0.f, 0.f, 0.f};

    #pragma unroll
    for (int tap = 0; tap < 9; ++tap) {
        int ky = tap / 3, kx = tap - 3 * ky;
        int yy = yo - 1 + ky;
        bool iny = (yy >= 0 && yy < H);
        int ry = yy - ylo;
        int pos0 = p0 - 1 + kx;
        int pos1 = p1 - 1 + kx;
        #pragma unroll
        for (int cs = 0; cs < 2; ++cs) {
            const f16x8* wf = wof + (size_t)((tap * 2 + cs) * 2) * 64 + lane;
            f16x8 a0 = wf[0];
            f16x8 a1 = wf[64];
            f16x8 b0 = splat8((_Float16)0.f), b1 = splat8((_Float16)0.f);
            if (iny && pos0 >= 0 && pos0 < W) {
                int jp = (cs * 4 + lk) ^ (pos0 & 7);
                b0 = *(const f16x8*)&band[(((size_t)ry * 128 + pos0) * 8 + jp) * 8];
            }
            if (iny && pos1 >= 0 && pos1 < W) {
                int jp = (cs * 4 + lk) ^ (pos1 & 7);
                b1 = *(const f16x8*)&band[(((size_t)ry * 128 + pos1) * 8 + jp) * 8];
            }
            oacc[0][0] = __builtin_amdgcn_mfma_f32_16x16x32_f16(a0, b0, oacc[0][0], 0, 0, 0);
            oacc[1][0] = __builtin_amdgcn_mfma_f32_16x16x32_f16(a1, b0, oacc[1][0], 0, 0, 0);
            oacc[0][1] = __builtin_amdgcn_mfma_f32_16x16x32_f16(a0, b1, oacc[0][1], 0, 0, 0);
            oacc[1][1] = __builtin_amdgcn_mfma_f32_16x16x32_f16(a1, b1, oacc[1][1], 0, 0, 0);
        }
    }

    // ======== record build: lane owns taps {2lk,2lk+1} (+8 if lk==0) for BOTH nt pixels ========
    int rbase0 = (rw * 128 + p0) * 9;
    int rbase1 = (rw * 128 + p1) * 9;
    auto build = [&](int tap, float offy, float offx, int p, int rbase) {
        int ky = tap / 3, kx = tap - 3 * ky;
        float py  = (float)(yo - 1 + ky) + offy;
        float pxf = (float)(p  - 1 + kx) + offx;
        float y0f = floorf(py), x0f = floorf(pxf);
        float fy = py - y0f, fx = pxf - x0f;
        int y0 = (int)y0f, x0 = (int)x0f;
        int y1 = y0 + 1, x1 = x0 + 1;
        float m00 = (1.f - fy) * (1.f - fx);
        float m01 = (1.f - fy) * fx;
        float m10 = fy * (1.f - fx);
        float m11 = fy * fx;
        if (y0 < 0 || y0 >= H) { m00 = 0.f; m01 = 0.f; }
        if (y1 < 0 || y1 >= H) { m10 = 0.f; m11 = 0.f; }
        if (x0 < 0 || x0 >= W) { m00 = 0.f; m10 = 0.f; }
        if (x1 < 0 || x1 >= W) { m01 = 0.f; m11 = 0.f; }
        int y0c = iclamp(y0, 0, H - 1), y1c = iclamp(y1, 0, H - 1);
        int x0c = iclamp(x0, 0, W - 1), x1c = iclamp(x1, 0, W - 1);
        int ry0 = y0c - ylo, ry1 = y1c - ylo;
        unsigned o0 = (ry0 < 0 || ry0 > nrm1) ? 0x8000u : 0u;
        unsigned o1 = (ry1 < 0 || ry1 > nrm1) ? 0x8000u : 0u;
        int r0 = iclamp(ry0, 0, 5), r1 = iclamp(ry1, 0, 5);
        unsigned f0 = (unsigned)(((r0 * 128 + x0c) << 3) | (x0c & 7)) | o0;
        unsigned f1 = (unsigned)(((r0 * 128 + x1c) << 3) | (x1c & 7)) | o0;
        unsigned f2 = (unsigned)(((r1 * 128 + x0c) << 3) | (x0c & 7)) | o1;
        unsigned f3 = (unsigned)(((r1 * 128 + x1c) << 3) | (x1c & 7)) | o1;
        uint4 rc;
        rc.x = packh2(m00, m01);
        rc.y = packh2(m10, m11);
        rc.z = f0 | (f1 << 16);
        rc.w = f2 | (f3 << 16);
        recs[rbase + tap] = rc;
        offs_f[rbase + tap] = packh2(offy, offx);
    };
    build(2 * lk,     oacc[0][0][0], oacc[0][0][1], p0, rbase0);
    build(2 * lk + 1, oacc[0][0][2], oacc[0][0][3], p0, rbase0);
    build(2 * lk,     oacc[0][1][0], oacc[0][1][1], p1, rbase1);
    build(2 * lk + 1, oacc[0][1][2], oacc[0][1][3], p1, rbase1);
    if (lk == 0) {
        build(8, oacc[1][0][0], oacc[1][0][1], p0, rbase0);
        build(8, oacc[1][1][0], oacc[1][1][1], p1, rbase1);
    }
    // no barrier: records are produced and consumed by the SAME wave

    // ======== phase 2: deformable conv (M=64, N=32/wave, K=576) ========
    f32x4 acc[4][2];   // [mt][nt]
    #pragma unroll
    for (int mt = 0; mt < 4; ++mt)
        #pragma unroll
        for (int nt = 0; nt < 2; ++nt) acc[mt][nt] = (f32x4){0.f, 0.f, 0.f, 0.f};

    const char* bb = (const char*)band;

    #pragma unroll
    for (int tap = 0; tap < 9; ++tap) {
        f16x8 bfr[2][2];   // [cs][nt]
        #pragma unroll
        for (int nt = 0; nt < 2; ++nt) {
            int rbase = nt ? rbase1 : rbase0;
            int pp    = nt ? p1 : p0;
            uint4 rc = recs[rbase + tap];
            union { unsigned u; _Float16 h[2]; } mA, mB;
            mA.u = rc.x; mB.u = rc.y;
            _Float16 h00 = mA.h[0], h01 = mA.h[1], h10 = mB.h[0], h11 = mB.h[1];
            int f0 = rc.z & 0xffff, f1 = rc.z >> 16;
            int f2 = rc.w & 0xffff, f3 = rc.w >> 16;
            bool fall = ((rc.z | rc.w) & 0x8000u) != 0;
            int a00 = (((f0 >> 3) & 1023) << 7) + ((lk ^ (f0 & 7)) << 4);
            int a01 = (((f1 >> 3) & 1023) << 7) + ((lk ^ (f1 & 7)) << 4);
            int a10 = (((f2 >> 3) & 1023) << 7) + ((lk ^ (f2 & 7)) << 4);
            int a11 = (((f3 >> 3) & 1023) << 7) + ((lk ^ (f3 & 7)) << 4);

            f16x8 g00 = *(const f16x8*)(bb + a00);
            f16x8 g01 = *(const f16x8*)(bb + a01);
            f16x8 g10 = *(const f16x8*)(bb + a10);
            f16x8 g11 = *(const f16x8*)(bb + a11);
            bfr[0][nt] = g00 * splat8(h00) + g01 * splat8(h01)
                       + g10 * splat8(h10) + g11 * splat8(h11);
            f16x8 k00 = *(const f16x8*)(bb + (a00 ^ 64));
            f16x8 k01 = *(const f16x8*)(bb + (a01 ^ 64));
            f16x8 k10 = *(const f16x8*)(bb + (a10 ^ 64));
            f16x8 k11 = *(const f16x8*)(bb + (a11 ^ 64));
            bfr[1][nt] = k00 * splat8(h00) + k01 * splat8(h01)
                       + k10 * splat8(h10) + k11 * splat8(h11);

            if (fall) {   // rare: corner row outside staged band -> recompute from global
                union { unsigned u; _Float16 h[2]; } of;
                of.u = offs_f[rbase + tap];
                float offy = (float)of.h[0], offx = (float)of.h[1];
                int ky = tap / 3, kx = tap - 3 * ky;
                float py  = (float)(yo - 1 + ky) + offy;
                float pxf = (float)(pp - 1 + kx) + offx;
                float y0f = floorf(py), x0f = floorf(pxf);
                float fy = py - y0f, fx = pxf - x0f;
                int y0 = (int)y0f, x0 = (int)x0f;
                int y1 = y0 + 1, x1 = x0 + 1;
                float n00 = (1.f - fy) * (1.f - fx);
                float n01 = (1.f - fy) * fx;
                float n10 = fy * (1.f - fx);
                float n11 = fy * fx;
                if (y0 < 0 || y0 >= H) { n00 = 0.f; n01 = 0.f; }
                if (y1 < 0 || y1 >= H) { n10 = 0.f; n11 = 0.f; }
                if (x0 < 0 || x0 >= W) { n00 = 0.f; n10 = 0.f; }
                if (x1 < 0 || x1 >= W) { n01 = 0.f; n11 = 0.f; }
                int y0c = iclamp(y0, 0, H - 1), y1c = iclamp(y1, 0, H - 1);
                int x0c = iclamp(x0, 0, W - 1), x1c = iclamp(x1, 0, W - 1);
                _Float16 q00 = (_Float16)n00, q01 = (_Float16)n01;
                _Float16 q10 = (_Float16)n10, q11 = (_Float16)n11;
                size_t i00 = ((size_t)y0c * W + x0c) * CIN, i01 = ((size_t)y0c * W + x1c) * CIN;
                size_t i10 = ((size_t)y1c * W + x0c) * CIN, i11 = ((size_t)y1c * W + x1c) * CIN;
                int c0 = lk * 8;
                bfr[0][nt] = (*(const f16x8*)&xb[i00 + c0]) * splat8(q00)
                           + (*(const f16x8*)&xb[i01 + c0]) * splat8(q01)
                           + (*(const f16x8*)&xb[i10 + c0]) * splat8(q10)
                           + (*(const f16x8*)&xb[i11 + c0]) * splat8(q11);
                int c1 = 32 + lk * 8;
                bfr[1][nt] = (*(const f16x8*)&xb[i00 + c1]) * splat8(q00)
                           + (*(const f16x8*)&xb[i01 + c1]) * splat8(q01)
                           + (*(const f16x8*)&xb[i10 + c1]) * splat8(q10)
                           + (*(const f16x8*)&xb[i11 + c1]) * splat8(q11);
            }
        }

        #pragma unroll
        for (int cs = 0; cs < 2; ++cs) {
            const f16x8* wf = wdf + (size_t)((tap * 2 + cs) * 4) * 64 + lane;
            #pragma unroll
            for (int mt = 0; mt < 4; ++mt) {
                f16x8 af = wf[mt * 64];
                acc[mt][0] = __builtin_amdgcn_mfma_f32_16x16x32_f16(af, bfr[cs][0], acc[mt][0], 0, 0, 0);
                acc[mt][1] = __builtin_amdgcn_mfma_f32_16x16x32_f16(af, bfr[cs][1], acc[mt][1], 0, 0, 0);
            }
        }
    }

    #pragma unroll
    for (int mt = 0; mt < 4; ++mt) {
        #pragma unroll
        for (int nt = 0; nt < 2; ++nt) {
            int pp = nt ? p1 : p0;
            #pragma unroll
            for (int r = 0; r < 4; ++r) {
                int oc = mt * 16 + lk * 4 + r;
                out[((size_t)b * OCH + oc) * HW + (size_t)yo * W + pp] = acc[mt][nt][r] + bias[oc];
            }
        }
    }
}

extern "C" void kernel_launch(void* const* d_in, const int* in_sizes, int n_in,
                              void* d_out, int out_size, void* d_ws, size_t ws_size,
                              hipStream_t stream) {
    const float* x     = (const float*)d_in[0];
    const float* w_off = (const float*)d_in[1];
    const float* w_def = (const float*)d_in[2];
    const float* b_def = (const float*)d_in[3];
    float* out = (float*)d_out;

    _Float16* xt  = (_Float16*)d_ws;                 // 8.4M f16 (16.8 MB)
    _Float16* wdf = xt + (size_t)BATCH * HW * CIN;   // 36,864 f16
    _Float16* wof = wdf + 36864;                     // 18,432 f16

    transpose_x_kernel<<<BATCH * H, 256, 0, stream>>>(x, xt);
    prep_wdf_kernel<<<(36864 + 255) / 256, 256, 0, stream>>>(w_def, wdf);
    prep_wof_kernel<<<(18432 + 255) / 256, 256, 0, stream>>>(w_off, wof);
    fused_deform_kernel<<<BATCH * H / 2, 512, 0, stream>>>(
        xt, (const f16x8*)wof, (const f16x8*)wdf, b_def, out);
}

// Round 13
// 54.048 us; speedup vs baseline: 1.2065x; 1.0198x over previous
//
#include <hip/hip_runtime.h>

#define BATCH 8
#define CIN 64
#define H 128
#define W 128
#define OCH 64
#define HW (H*W)
#define OFFCH 18

using f16x8 = __attribute__((ext_vector_type(8))) _Float16;
using f32x4 = __attribute__((ext_vector_type(4))) float;

static __device__ __forceinline__ int iclamp(int v, int lo, int hi) {
    return v < lo ? lo : (v > hi ? hi : v);
}
static __device__ __forceinline__ f16x8 splat8(_Float16 v) {
    return (f16x8){v, v, v, v, v, v, v, v};
}
static __device__ __forceinline__ unsigned packh2(float a, float b) {
    union { _Float16 h[2]; unsigned u; } pk;
    pk.h[0] = (_Float16)a; pk.h[1] = (_Float16)b;
    return pk.u;
}

// ---------------- transpose x [B][C][H][W] f32 -> xt [B][H][W][C] f16 ----------------
__global__ __launch_bounds__(256) void transpose_x_kernel(
    const float* __restrict__ x, _Float16* __restrict__ xt)
{
    __shared__ float ls[CIN][129];
    int bid = blockIdx.x;          // B*H = 1024
    int b = bid >> 7, y = bid & 127;
    int t = threadIdx.x;

    const float* xb = x + (size_t)b * CIN * HW + (size_t)y * W;
    #pragma unroll 4
    for (int i = 0; i < 32; ++i) {
        int c = i * 2 + (t >> 7);
        ls[c][t & 127] = xb[(size_t)c * HW + (t & 127)];
    }
    __syncthreads();

    _Float16* xo = xt + (size_t)(b * H + y) * W * CIN;
    #pragma unroll 4
    for (int i = 0; i < 16; ++i) {
        int px = i * 8 + (t >> 5);
        int c  = (t & 31) * 2;
        _Float16 a0 = (_Float16)ls[c][px];
        _Float16 a1 = (_Float16)ls[c + 1][px];
        union { _Float16 h[2]; unsigned int u; } pk;
        pk.h[0] = a0; pk.h[1] = a1;
        *(unsigned int*)&xo[(size_t)px * CIN + c] = pk.u;
    }
}

// ---------------- prep w_deform -> f16 MFMA A-frag order ----------------
__global__ __launch_bounds__(256) void prep_wdf_kernel(
    const float* __restrict__ w, _Float16* __restrict__ wdf)
{
    int i = blockIdx.x * 256 + threadIdx.x;   // 9*2*4*64*8 = 36864
    if (i >= 9 * 2 * 4 * 64 * 8) return;
    int j    = i & 7;
    int lane = (i >> 3) & 63;
    int mt   = (i >> 9) & 3;
    int cs   = (i >> 11) & 1;
    int tap  = i >> 12;
    int oc = mt * 16 + (lane & 15);
    int c  = cs * 32 + (lane >> 4) * 8 + j;
    wdf[i] = (_Float16)w[(oc * CIN + c) * 9 + tap];
}

// ---------------- prep w_offset -> f16 MFMA A-frag order (M padded 18->32) ----------------
__global__ __launch_bounds__(256) void prep_wof_kernel(
    const float* __restrict__ w, _Float16* __restrict__ wof)
{
    int i = blockIdx.x * 256 + threadIdx.x;   // 9*2*2*64*8 = 18432
    if (i >= 9 * 2 * 2 * 64 * 8) return;
    int j    = i & 7;
    int lane = (i >> 3) & 63;
    int mt   = (i >> 9) & 1;
    int cs   = (i >> 10) & 1;
    int tap  = i >> 11;
    int oc = mt * 16 + (lane & 15);
    int c  = cs * 32 + (lane >> 4) * 8 + j;
    wof[i] = (oc < OFFCH) ? (_Float16)w[(oc * CIN + c) * 9 + tap] : (_Float16)0.f;
}

// ---------------- fused offset-conv + deformable conv ----------------
// Grid 256 = (b, yquad); 1024 threads = 16 waves; wave w: row y+(w>>2), px (w&3)*32+{0,16}+l15.
// N=32/wave (A-frag amortized over 2 B-frags). Rows [y-2, y+5] staged in LDS (128 KB).
// Bilinear records held in PRODUCER-LANE REGISTERS, consumed via __shfl (no recs LDS).
__global__ __launch_bounds__(1024, 4) void fused_deform_kernel(
    const _Float16* __restrict__ xt, const f16x8* __restrict__ wof,
    const f16x8* __restrict__ wdf, const float* __restrict__ bias,
    float* __restrict__ out)
{
    __shared__ _Float16 band[8 * 128 * CIN];       // 128 KB; chunk-swizzled per pixel

    int bid  = blockIdx.x;           // 256
    int b    = bid & 7;              // one batch per XCD
    int y    = (bid >> 3) * 4;       // block covers rows y..y+3
    int tid  = threadIdx.x;
    int lane = tid & 63;
    int wave = tid >> 6;             // 0..15
    int l15  = lane & 15;
    int lk   = lane >> 4;
    int yo   = y + (wave >> 2);      // this wave's output row
    int pxbase = (wave & 3) * 32;
    int p0   = pxbase + l15;         // nt=0 pixel
    int p1   = p0 + 16;              // nt=1 pixel

    int ylo = y - 2 < 0 ? 0 : y - 2;
    int yhi = y + 5 > H - 1 ? H - 1 : y + 5;
    int nrm1 = yhi - ylo;

    const _Float16* xb = xt + (size_t)b * HW * CIN;

    // ---- stage band rows [ylo..yhi] -> LDS; 1024 chunks/row, 1 per thread ----
    {
        int spx = tid >> 3;
        int sjl = tid & 7;
        int sjp = sjl ^ (spx & 7);
        #pragma unroll
        for (int r = 0; r < 8; ++r) {
            int gy = ylo + r;
            if (gy > yhi) break;
            *(f16x8*)&band[(((size_t)r * 128 + spx) * 8 + sjp) * 8] =
                *(const f16x8*)&xb[((size_t)gy * W + spx) * CIN + sjl * 8];
        }
    }
    __syncthreads();

    // ======== phase 1: offset conv (M=32 padded, N=32/wave, K=576), B from band ========
    f32x4 oacc[2][2];   // [mt][nt]
    #pragma unroll
    for (int mt = 0; mt < 2; ++mt)
        #pragma unroll
        for (int nt = 0; nt < 2; ++nt) oacc[mt][nt] = (f32x4){0.f, 0.f, 0.f, 0.f};

    #pragma unroll
    for (int tap = 0; tap < 9; ++tap) {
        int ky = tap / 3, kx = tap - 3 * ky;
        int yy = yo - 1 + ky;
        bool iny = (yy >= 0 && yy < H);
        int ry = yy - ylo;
        int pos0 = p0 - 1 + kx;
        int pos1 = p1 - 1 + kx;
        #pragma unroll
        for (int cs = 0; cs < 2; ++cs) {
            const f16x8* wf = wof + (size_t)((tap * 2 + cs) * 2) * 64 + lane;
            f16x8 a0 = wf[0];
            f16x8 a1 = wf[64];
            f16x8 b0 = splat8((_Float16)0.f), b1 = splat8((_Float16)0.f);
            if (iny && pos0 >= 0 && pos0 < W) {
                int jp = (cs * 4 + lk) ^ (pos0 & 7);
                b0 = *(const f16x8*)&band[(((size_t)ry * 128 + pos0) * 8 + jp) * 8];
            }
            if (iny && pos1 >= 0 && pos1 < W) {
                int jp = (cs * 4 + lk) ^ (pos1 & 7);
                b1 = *(const f16x8*)&band[(((size_t)ry * 128 + pos1) * 8 + jp) * 8];
            }
            oacc[0][0] = __builtin_amdgcn_mfma_f32_16x16x32_f16(a0, b0, oacc[0][0], 0, 0, 0);
            oacc[1][0] = __builtin_amdgcn_mfma_f32_16x16x32_f16(a1, b0, oacc[1][0], 0, 0, 0);
            oacc[0][1] = __builtin_amdgcn_mfma_f32_16x16x32_f16(a0, b1, oacc[0][1], 0, 0, 0);
            oacc[1][1] = __builtin_amdgcn_mfma_f32_16x16x32_f16(a1, b1, oacc[1][1], 0, 0, 0);
        }
    }

    // ======== record build into REGISTERS: lane (l15,lk) owns taps {2lk,2lk+1} (+8 if lk==0) ========
    uint4 rcA, rcB, rcC, rcD;                    // [tap even/odd][p0/p1]
    uint4 rc8a = {0,0,0,0}, rc8b = {0,0,0,0};    // tap 8 (valid in lk==0 lanes)
    unsigned ofA, ofB, ofC, ofD, of8a = 0, of8b = 0;

    auto build = [&](int tap, float offy, float offx, int p, uint4& rc, unsigned& of) {
        int ky = tap / 3, kx = tap - 3 * ky;
        float py  = (float)(yo - 1 + ky) + offy;
        float pxf = (float)(p  - 1 + kx) + offx;
        float y0f = floorf(py), x0f = floorf(pxf);
        float fy = py - y0f, fx = pxf - x0f;
        int y0 = (int)y0f, x0 = (int)x0f;
        int y1 = y0 + 1, x1 = x0 + 1;
        float m00 = (1.f - fy) * (1.f - fx);
        float m01 = (1.f - fy) * fx;
        float m10 = fy * (1.f - fx);
        float m11 = fy * fx;
        if (y0 < 0 || y0 >= H) { m00 = 0.f; m01 = 0.f; }
        if (y1 < 0 || y1 >= H) { m10 = 0.f; m11 = 0.f; }
        if (x0 < 0 || x0 >= W) { m00 = 0.f; m10 = 0.f; }
        if (x1 < 0 || x1 >= W) { m01 = 0.f; m11 = 0.f; }
        int y0c = iclamp(y0, 0, H - 1), y1c = iclamp(y1, 0, H - 1);
        int x0c = iclamp(x0, 0, W - 1), x1c = iclamp(x1, 0, W - 1);
        int ry0 = y0c - ylo, ry1 = y1c - ylo;
        unsigned o0 = (ry0 < 0 || ry0 > nrm1) ? 0x8000u : 0u;
        unsigned o1 = (ry1 < 0 || ry1 > nrm1) ? 0x8000u : 0u;
        int r0 = iclamp(ry0, 0, 7), r1 = iclamp(ry1, 0, 7);
        unsigned f0 = (unsigned)(((r0 * 128 + x0c) << 3) | (x0c & 7)) | o0;
        unsigned f1 = (unsigned)(((r0 * 128 + x1c) << 3) | (x1c & 7)) | o0;
        unsigned f2 = (unsigned)(((r1 * 128 + x0c) << 3) | (x0c & 7)) | o1;
        unsigned f3 = (unsigned)(((r1 * 128 + x1c) << 3) | (x1c & 7)) | o1;
        rc.x = packh2(m00, m01);
        rc.y = packh2(m10, m11);
        rc.z = f0 | (f1 << 16);
        rc.w = f2 | (f3 << 16);
        of   = packh2(offy, offx);
    };
    build(2 * lk,     oacc[0][0][0], oacc[0][0][1], p0, rcA, ofA);
    build(2 * lk + 1, oacc[0][0][2], oacc[0][0][3], p0, rcB, ofB);
    build(2 * lk,     oacc[0][1][0], oacc[0][1][1], p1, rcC, ofC);
    build(2 * lk + 1, oacc[0][1][2], oacc[0][1][3], p1, rcD, ofD);
    if (lk == 0) {
        build(8, oacc[1][0][0], oacc[1][0][1], p0, rc8a, of8a);
        build(8, oacc[1][1][0], oacc[1][1][1], p1, rc8b, of8b);
    }
    // no barrier: records travel intra-wave via shfl

    // ======== phase 2: deformable conv (M=64, N=32/wave, K=576) ========
    f32x4 acc[4][2];   // [mt][nt]
    #pragma unroll
    for (int mt = 0; mt < 4; ++mt)
        #pragma unroll
        for (int nt = 0; nt < 2; ++nt) acc[mt][nt] = (f32x4){0.f, 0.f, 0.f, 0.f};

    const char* bb = (const char*)band;

    #pragma unroll
    for (int tap = 0; tap < 9; ++tap) {
        int src = (tap < 8) ? ((tap >> 1) * 16 + l15) : l15;
        f16x8 bfr[2][2];   // [cs][nt]
        #pragma unroll
        for (int nt = 0; nt < 2; ++nt) {
            int pp = nt ? p1 : p0;
            uint4 rsel;
            unsigned osel;
            if (tap < 8) {
                if (tap & 1) { rsel = nt ? rcD : rcB; osel = nt ? ofD : ofB; }
                else         { rsel = nt ? rcC : rcA; osel = nt ? ofC : ofA; }
            } else         { rsel = nt ? rc8b : rc8a; osel = nt ? of8b : of8a; }
            uint4 rc;
            rc.x = (unsigned)__shfl((int)rsel.x, src, 64);
            rc.y = (unsigned)__shfl((int)rsel.y, src, 64);
            rc.z = (unsigned)__shfl((int)rsel.z, src, 64);
            rc.w = (unsigned)__shfl((int)rsel.w, src, 64);

            union { unsigned u; _Float16 h[2]; } mA, mB;
            mA.u = rc.x; mB.u = rc.y;
            _Float16 h00 = mA.h[0], h01 = mA.h[1], h10 = mB.h[0], h11 = mB.h[1];
            int f0 = rc.z & 0xffff, f1 = rc.z >> 16;
            int f2 = rc.w & 0xffff, f3 = rc.w >> 16;
            bool fall = ((rc.z | rc.w) & 0x8000u) != 0;
            int a00 = (((f0 >> 3) & 1023) << 7) + ((lk ^ (f0 & 7)) << 4);
            int a01 = (((f1 >> 3) & 1023) << 7) + ((lk ^ (f1 & 7)) << 4);
            int a10 = (((f2 >> 3) & 1023) << 7) + ((lk ^ (f2 & 7)) << 4);
            int a11 = (((f3 >> 3) & 1023) << 7) + ((lk ^ (f3 & 7)) << 4);

            f16x8 g00 = *(const f16x8*)(bb + a00);
            f16x8 g01 = *(const f16x8*)(bb + a01);
            f16x8 g10 = *(const f16x8*)(bb + a10);
            f16x8 g11 = *(const f16x8*)(bb + a11);
            bfr[0][nt] = g00 * splat8(h00) + g01 * splat8(h01)
                       + g10 * splat8(h10) + g11 * splat8(h11);
            f16x8 k00 = *(const f16x8*)(bb + (a00 ^ 64));
            f16x8 k01 = *(const f16x8*)(bb + (a01 ^ 64));
            f16x8 k10 = *(const f16x8*)(bb + (a10 ^ 64));
            f16x8 k11 = *(const f16x8*)(bb + (a11 ^ 64));
            bfr[1][nt] = k00 * splat8(h00) + k01 * splat8(h01)
                       + k10 * splat8(h10) + k11 * splat8(h11);

            if (__any(fall)) {   // rare: corner row outside staged band
                unsigned ofu = (unsigned)__shfl((int)osel, src, 64);
                if (fall) {
                    union { unsigned u; _Float16 h[2]; } of;
                    of.u = ofu;
                    float offy = (float)of.h[0], offx = (float)of.h[1];
                    int ky = tap / 3, kx = tap - 3 * ky;
                    float py  = (float)(yo - 1 + ky) + offy;
                    float pxf = (float)(pp - 1 + kx) + offx;
                    float y0f = floorf(py), x0f = floorf(pxf);
                    float fy = py - y0f, fx = pxf - x0f;
                    int y0 = (int)y0f, x0 = (int)x0f;
                    int y1 = y0 + 1, x1 = x0 + 1;
                    float n00 = (1.f - fy) * (1.f - fx);
                    float n01 = (1.f - fy) * fx;
                    float n10 = fy * (1.f - fx);
                    float n11 = fy * fx;
                    if (y0 < 0 || y0 >= H) { n00 = 0.f; n01 = 0.f; }
                    if (y1 < 0 || y1 >= H) { n10 = 0.f; n11 = 0.f; }
                    if (x0 < 0 || x0 >= W) { n00 = 0.f; n10 = 0.f; }
                    if (x1 < 0 || x1 >= W) { n01 = 0.f; n11 = 0.f; }
                    int y0c = iclamp(y0, 0, H - 1), y1c = iclamp(y1, 0, H - 1);
                    int x0c = iclamp(x0, 0, W - 1), x1c = iclamp(x1, 0, W - 1);
                    _Float16 q00 = (_Float16)n00, q01 = (_Float16)n01;
                    _Float16 q10 = (_Float16)n10, q11 = (_Float16)n11;
                    size_t i00 = ((size_t)y0c * W + x0c) * CIN, i01 = ((size_t)y0c * W + x1c) * CIN;
                    size_t i10 = ((size_t)y1c * W + x0c) * CIN, i11 = ((size_t)y1c * W + x1c) * CIN;
                    int c0 = lk * 8;
                    bfr[0][nt] = (*(const f16x8*)&xb[i00 + c0]) * splat8(q00)
                               + (*(const f16x8*)&xb[i01 + c0]) * splat8(q01)
                               + (*(const f16x8*)&xb[i10 + c0]) * splat8(q10)
                               + (*(const f16x8*)&xb[i11 + c0]) * splat8(q11);
                    int c1 = 32 + lk * 8;
                    bfr[1][nt] = (*(const f16x8*)&xb[i00 + c1]) * splat8(q00)
                               + (*(const f16x8*)&xb[i01 + c1]) * splat8(q01)
                               + (*(const f16x8*)&xb[i10 + c1]) * splat8(q10)
                               + (*(const f16x8*)&xb[i11 + c1]) * splat8(q11);
                }
            }
        }

        #pragma unroll
        for (int cs = 0; cs < 2; ++cs) {
            const f16x8* wf = wdf + (size_t)((tap * 2 + cs) * 4) * 64 + lane;
            #pragma unroll
            for (int mt = 0; mt < 4; ++mt) {
                f16x8 af = wf[mt * 64];
                acc[mt][0] = __builtin_amdgcn_mfma_f32_16x16x32_f16(af, bfr[cs][0], acc[mt][0], 0, 0, 0);
                acc[mt][1] = __builtin_amdgcn_mfma_f32_16x16x32_f16(af, bfr[cs][1], acc[mt][1], 0, 0, 0);
            }
        }
    }

    #pragma unroll
    for (int mt = 0; mt < 4; ++mt) {
        #pragma unroll
        for (int nt = 0; nt < 2; ++nt) {
            int pp = nt ? p1 : p0;
            #pragma unroll
            for (int r = 0; r < 4; ++r) {
                int oc = mt * 16 + lk * 4 + r;
                out[((size_t)b * OCH + oc) * HW + (size_t)yo * W + pp] = acc[mt][nt][r] + bias[oc];
            }
        }
    }
}

extern "C" void kernel_launch(void* const* d_in, const int* in_sizes, int n_in,
                              void* d_out, int out_size, void* d_ws, size_t ws_size,
                              hipStream_t stream) {
    const float* x     = (const float*)d_in[0];
    const float* w_off = (const float*)d_in[1];
    const float* w_def = (const float*)d_in[2];
    const float* b_def = (const float*)d_in[3];
    float* out = (float*)d_out;

    _Float16* xt  = (_Float16*)d_ws;                 // 8.4M f16 (16.8 MB)
    _Float16* wdf = xt + (size_t)BATCH * HW * CIN;   // 36,864 f16
    _Float16* wof = wdf + 36864;                     // 18,432 f16

    transpose_x_kernel<<<BATCH * H, 256, 0, stream>>>(x, xt);
    prep_wdf_kernel<<<(36864 + 255) / 256, 256, 0, stream>>>(w_def, wdf);
    prep_wof_kernel<<<(18432 + 255) / 256, 256, 0, stream>>>(w_off, wof);
    fused_deform_kernel<<<BATCH * H / 4, 1024, 0, stream>>>(
        xt, (const f16x8*)wof, (const f16x8*)wdf, b_def, out);
}

// Round 14
// 47.600 us; speedup vs baseline: 1.3700x; 1.1355x over previous
//
#include <hip/hip_runtime.h>

#define BATCH 8
#define CIN 64
#define H 128
#define W 128
#define OCH 64
#define HW (H*W)
#define OFFCH 18

using f16x8 = __attribute__((ext_vector_type(8))) _Float16;
using f32x4 = __attribute__((ext_vector_type(4))) float;

static __device__ __forceinline__ int iclamp(int v, int lo, int hi) {
    return v < lo ? lo : (v > hi ? hi : v);
}
static __device__ __forceinline__ f16x8 splat8(_Float16 v) {
    return (f16x8){v, v, v, v, v, v, v, v};
}
static __device__ __forceinline__ unsigned packh2(float a, float b) {
    union { _Float16 h[2]; unsigned u; } pk;
    pk.h[0] = (_Float16)a; pk.h[1] = (_Float16)b;
    return pk.u;
}

// ---------------- prep both weight tensors -> f16 MFMA A-frag order (one launch) ----------------
// i in [0, 36864):           wdf[((tap*2+cs)*4+mt)*512 + lane*8 + j]
// i in [36864, 36864+18432): wof[((tap*2+cs)*2+mt)*512 + lane*8 + j], M padded 18->32
__global__ __launch_bounds__(256) void prep_w_kernel(
    const float* __restrict__ wd, const float* __restrict__ wo,
    _Float16* __restrict__ wdf, _Float16* __restrict__ wof)
{
    int i = blockIdx.x * 256 + threadIdx.x;   // 55296 total
    if (i < 36864) {
        int j    = i & 7;
        int lane = (i >> 3) & 63;
        int mt   = (i >> 9) & 3;
        int cs   = (i >> 11) & 1;
        int tap  = i >> 12;
        int oc = mt * 16 + (lane & 15);
        int c  = cs * 32 + (lane >> 4) * 8 + j;
        wdf[i] = (_Float16)wd[(oc * CIN + c) * 9 + tap];
    } else if (i < 36864 + 18432) {
        int k = i - 36864;
        int j    = k & 7;
        int lane = (k >> 3) & 63;
        int mt   = (k >> 9) & 1;
        int cs   = (k >> 10) & 1;
        int tap  = k >> 11;
        int oc = mt * 16 + (lane & 15);
        int c  = cs * 32 + (lane >> 4) * 8 + j;
        wof[k] = (oc < OFFCH) ? (_Float16)wo[(oc * CIN + c) * 9 + tap] : (_Float16)0.f;
    }
}

// ---------------- fused: stage(NCHW f32 -> f16 band) + offset conv + deformable conv ----------------
// Grid 256 = (b, yquad); 1024 threads = 16 waves; wave w: row y+(w>>2), px (w&3)*32+{0,16}+l15.
// N=32/wave. Rows [y-2, y+5] staged in LDS (128 KB) DIRECTLY from x (transpose in registers).
// Bilinear records in producer-lane registers, consumed via __shfl. No xt intermediate.
__global__ __launch_bounds__(1024, 4) void fused_deform_kernel(
    const float* __restrict__ x, const f16x8* __restrict__ wof,
    const f16x8* __restrict__ wdf, const float* __restrict__ bias,
    float* __restrict__ out)
{
    __shared__ _Float16 band[8 * 128 * CIN];       // 128 KB; chunk-swizzled per pixel

    int bid  = blockIdx.x;           // 256
    int b    = bid & 7;              // one batch per XCD
    int y    = (bid >> 3) * 4;       // block covers rows y..y+3
    int tid  = threadIdx.x;
    int lane = tid & 63;
    int wave = tid >> 6;             // 0..15
    int l15  = lane & 15;
    int lk   = lane >> 4;
    int yo   = y + (wave >> 2);      // this wave's output row
    int pxbase = (wave & 3) * 32;
    int p0   = pxbase + l15;         // nt=0 pixel
    int p1   = p0 + 16;              // nt=1 pixel

    int ylo = y - 2 < 0 ? 0 : y - 2;
    int yhi = y + 5 > H - 1 ? H - 1 : y + 5;
    int nrm1 = yhi - ylo;

    const float* xbf = x + (size_t)b * CIN * HW;

    // ---- stage band rows [ylo..yhi] directly from NCHW f32 ----
    // thread = (px_s, cg): 8 coalesced f32 loads (consecutive px per lane), cvt, 1 b128 write.
    {
        int px_s = tid & 127;
        int cg   = tid >> 7;                 // channel group 0..7
        int jp_s = cg ^ (px_s & 7);
        const float* xcg = xbf + (size_t)(cg * 8) * HW + px_s;
        #pragma unroll
        for (int r = 0; r < 8; ++r) {
            int gy = ylo + r;
            if (gy > yhi) break;
            const float* xp = xcg + (size_t)gy * W;
            f16x8 v;
            #pragma unroll
            for (int j = 0; j < 8; ++j) v[j] = (_Float16)xp[(size_t)j * HW];
            *(f16x8*)&band[(((size_t)r * 128 + px_s) * 8 + jp_s) * 8] = v;
        }
    }
    __syncthreads();

    // ======== phase 1: offset conv (M=32 padded, N=32/wave, K=576), B from band ========
    f32x4 oacc[2][2];   // [mt][nt]
    #pragma unroll
    for (int mt = 0; mt < 2; ++mt)
        #pragma unroll
        for (int nt = 0; nt < 2; ++nt) oacc[mt][nt] = (f32x4){0.f, 0.f, 0.f, 0.f};

    #pragma unroll
    for (int tap = 0; tap < 9; ++tap) {
        int ky = tap / 3, kx = tap - 3 * ky;
        int yy = yo - 1 + ky;
        bool iny = (yy >= 0 && yy < H);
        int ry = yy - ylo;
        int pos0 = p0 - 1 + kx;
        int pos1 = p1 - 1 + kx;
        #pragma unroll
        for (int cs = 0; cs < 2; ++cs) {
            const f16x8* wf = wof + (size_t)((tap * 2 + cs) * 2) * 64 + lane;
            f16x8 a0 = wf[0];
            f16x8 a1 = wf[64];
            f16x8 b0 = splat8((_Float16)0.f), b1 = splat8((_Float16)0.f);
            if (iny && pos0 >= 0 && pos0 < W) {
                int jp = (cs * 4 + lk) ^ (pos0 & 7);
                b0 = *(const f16x8*)&band[(((size_t)ry * 128 + pos0) * 8 + jp) * 8];
            }
            if (iny && pos1 >= 0 && pos1 < W) {
                int jp = (cs * 4 + lk) ^ (pos1 & 7);
                b1 = *(const f16x8*)&band[(((size_t)ry * 128 + pos1) * 8 + jp) * 8];
            }
            oacc[0][0] = __builtin_amdgcn_mfma_f32_16x16x32_f16(a0, b0, oacc[0][0], 0, 0, 0);
            oacc[1][0] = __builtin_amdgcn_mfma_f32_16x16x32_f16(a1, b0, oacc[1][0], 0, 0, 0);
            oacc[0][1] = __builtin_amdgcn_mfma_f32_16x16x32_f16(a0, b1, oacc[0][1], 0, 0, 0);
            oacc[1][1] = __builtin_amdgcn_mfma_f32_16x16x32_f16(a1, b1, oacc[1][1], 0, 0, 0);
        }
    }

    // ======== record build into REGISTERS: lane (l15,lk) owns taps {2lk,2lk+1} (+8 if lk==0) ========
    uint4 rcA, rcB, rcC, rcD;                    // [tap even/odd][p0/p1]
    uint4 rc8a = {0,0,0,0}, rc8b = {0,0,0,0};    // tap 8 (valid in lk==0 lanes)
    unsigned ofA, ofB, ofC, ofD, of8a = 0, of8b = 0;

    auto build = [&](int tap, float offy, float offx, int p, uint4& rc, unsigned& of) {
        int ky = tap / 3, kx = tap - 3 * ky;
        float py  = (float)(yo - 1 + ky) + offy;
        float pxf = (float)(p  - 1 + kx) + offx;
        float y0f = floorf(py), x0f = floorf(pxf);
        float fy = py - y0f, fx = pxf - x0f;
        int y0 = (int)y0f, x0 = (int)x0f;
        int y1 = y0 + 1, x1 = x0 + 1;
        float m00 = (1.f - fy) * (1.f - fx);
        float m01 = (1.f - fy) * fx;
        float m10 = fy * (1.f - fx);
        float m11 = fy * fx;
        if (y0 < 0 || y0 >= H) { m00 = 0.f; m01 = 0.f; }
        if (y1 < 0 || y1 >= H) { m10 = 0.f; m11 = 0.f; }
        if (x0 < 0 || x0 >= W) { m00 = 0.f; m10 = 0.f; }
        if (x1 < 0 || x1 >= W) { m01 = 0.f; m11 = 0.f; }
        int y0c = iclamp(y0, 0, H - 1), y1c = iclamp(y1, 0, H - 1);
        int x0c = iclamp(x0, 0, W - 1), x1c = iclamp(x1, 0, W - 1);
        int ry0 = y0c - ylo, ry1 = y1c - ylo;
        unsigned o0 = (ry0 < 0 || ry0 > nrm1) ? 0x8000u : 0u;
        unsigned o1 = (ry1 < 0 || ry1 > nrm1) ? 0x8000u : 0u;
        int r0 = iclamp(ry0, 0, 7), r1 = iclamp(ry1, 0, 7);
        unsigned f0 = (unsigned)(((r0 * 128 + x0c) << 3) | (x0c & 7)) | o0;
        unsigned f1 = (unsigned)(((r0 * 128 + x1c) << 3) | (x1c & 7)) | o0;
        unsigned f2 = (unsigned)(((r1 * 128 + x0c) << 3) | (x0c & 7)) | o1;
        unsigned f3 = (unsigned)(((r1 * 128 + x1c) << 3) | (x1c & 7)) | o1;
        rc.x = packh2(m00, m01);
        rc.y = packh2(m10, m11);
        rc.z = f0 | (f1 << 16);
        rc.w = f2 | (f3 << 16);
        of   = packh2(offy, offx);
    };
    build(2 * lk,     oacc[0][0][0], oacc[0][0][1], p0, rcA, ofA);
    build(2 * lk + 1, oacc[0][0][2], oacc[0][0][3], p0, rcB, ofB);
    build(2 * lk,     oacc[0][1][0], oacc[0][1][1], p1, rcC, ofC);
    build(2 * lk + 1, oacc[0][1][2], oacc[0][1][3], p1, rcD, ofD);
    if (lk == 0) {
        build(8, oacc[1][0][0], oacc[1][0][1], p0, rc8a, of8a);
        build(8, oacc[1][1][0], oacc[1][1][1], p1, rc8b, of8b);
    }
    // no barrier: records travel intra-wave via shfl

    // ======== phase 2: deformable conv (M=64, N=32/wave, K=576) ========
    f32x4 acc[4][2];   // [mt][nt]
    #pragma unroll
    for (int mt = 0; mt < 4; ++mt)
        #pragma unroll
        for (int nt = 0; nt < 2; ++nt) acc[mt][nt] = (f32x4){0.f, 0.f, 0.f, 0.f};

    const char* bb = (const char*)band;

    #pragma unroll
    for (int tap = 0; tap < 9; ++tap) {
        int src = (tap < 8) ? ((tap >> 1) * 16 + l15) : l15;
        f16x8 bfr[2][2];   // [cs][nt]
        #pragma unroll
        for (int nt = 0; nt < 2; ++nt) {
            int pp = nt ? p1 : p0;
            uint4 rsel;
            unsigned osel;
            if (tap < 8) {
                if (tap & 1) { rsel = nt ? rcD : rcB; osel = nt ? ofD : ofB; }
                else         { rsel = nt ? rcC : rcA; osel = nt ? ofC : ofA; }
            } else         { rsel = nt ? rc8b : rc8a; osel = nt ? of8b : of8a; }
            uint4 rc;
            rc.x = (unsigned)__shfl((int)rsel.x, src, 64);
            rc.y = (unsigned)__shfl((int)rsel.y, src, 64);
            rc.z = (unsigned)__shfl((int)rsel.z, src, 64);
            rc.w = (unsigned)__shfl((int)rsel.w, src, 64);

            union { unsigned u; _Float16 h[2]; } mA, mB;
            mA.u = rc.x; mB.u = rc.y;
            _Float16 h00 = mA.h[0], h01 = mA.h[1], h10 = mB.h[0], h11 = mB.h[1];
            int f0 = rc.z & 0xffff, f1 = rc.z >> 16;
            int f2 = rc.w & 0xffff, f3 = rc.w >> 16;
            bool fall = ((rc.z | rc.w) & 0x8000u) != 0;
            int a00 = (((f0 >> 3) & 1023) << 7) + ((lk ^ (f0 & 7)) << 4);
            int a01 = (((f1 >> 3) & 1023) << 7) + ((lk ^ (f1 & 7)) << 4);
            int a10 = (((f2 >> 3) & 1023) << 7) + ((lk ^ (f2 & 7)) << 4);
            int a11 = (((f3 >> 3) & 1023) << 7) + ((lk ^ (f3 & 7)) << 4);

            f16x8 g00 = *(const f16x8*)(bb + a00);
            f16x8 g01 = *(const f16x8*)(bb + a01);
            f16x8 g10 = *(const f16x8*)(bb + a10);
            f16x8 g11 = *(const f16x8*)(bb + a11);
            bfr[0][nt] = g00 * splat8(h00) + g01 * splat8(h01)
                       + g10 * splat8(h10) + g11 * splat8(h11);
            f16x8 k00 = *(const f16x8*)(bb + (a00 ^ 64));
            f16x8 k01 = *(const f16x8*)(bb + (a01 ^ 64));
            f16x8 k10 = *(const f16x8*)(bb + (a10 ^ 64));
            f16x8 k11 = *(const f16x8*)(bb + (a11 ^ 64));
            bfr[1][nt] = k00 * splat8(h00) + k01 * splat8(h01)
                       + k10 * splat8(h10) + k11 * splat8(h11);

            if (__any(fall)) {   // rare: corner row outside staged band -> NCHW f32 gather
                unsigned ofu = (unsigned)__shfl((int)osel, src, 64);
                if (fall) {
                    union { unsigned u; _Float16 h[2]; } of;
                    of.u = ofu;
                    float offy = (float)of.h[0], offx = (float)of.h[1];
                    int ky = tap / 3, kx = tap - 3 * ky;
                    float py  = (float)(yo - 1 + ky) + offy;
                    float pxf = (float)(pp - 1 + kx) + offx;
                    float y0f = floorf(py), x0f = floorf(pxf);
                    float fy = py - y0f, fx = pxf - x0f;
                    int y0 = (int)y0f, x0 = (int)x0f;
                    int y1 = y0 + 1, x1 = x0 + 1;
                    float n00 = (1.f - fy) * (1.f - fx);
                    float n01 = (1.f - fy) * fx;
                    float n10 = fy * (1.f - fx);
                    float n11 = fy * fx;
                    if (y0 < 0 || y0 >= H) { n00 = 0.f; n01 = 0.f; }
                    if (y1 < 0 || y1 >= H) { n10 = 0.f; n11 = 0.f; }
                    if (x0 < 0 || x0 >= W) { n00 = 0.f; n10 = 0.f; }
                    if (x1 < 0 || x1 >= W) { n01 = 0.f; n11 = 0.f; }
                    int y0c = iclamp(y0, 0, H - 1), y1c = iclamp(y1, 0, H - 1);
                    int x0c = iclamp(x0, 0, W - 1), x1c = iclamp(x1, 0, W - 1);
                    int i00 = y0c * W + x0c, i01 = y0c * W + x1c;
                    int i10 = y1c * W + x0c, i11 = y1c * W + x1c;
                    #pragma unroll
                    for (int cs = 0; cs < 2; ++cs) {
                        const float* xc = xbf + (size_t)(cs * 32 + lk * 8) * HW;
                        #pragma unroll
                        for (int j = 0; j < 8; ++j) {
                            float v = n00 * xc[i00] + n01 * xc[i01]
                                    + n10 * xc[i10] + n11 * xc[i11];
                            bfr[cs][nt][j] = (_Float16)v;
                            xc += HW;
                        }
                    }
                }
            }
        }

        #pragma unroll
        for (int cs = 0; cs < 2; ++cs) {
            const f16x8* wf = wdf + (size_t)((tap * 2 + cs) * 4) * 64 + lane;
            #pragma unroll
            for (int mt = 0; mt < 4; ++mt) {
                f16x8 af = wf[mt * 64];
                acc[mt][0] = __builtin_amdgcn_mfma_f32_16x16x32_f16(af, bfr[cs][0], acc[mt][0], 0, 0, 0);
                acc[mt][1] = __builtin_amdgcn_mfma_f32_16x16x32_f16(af, bfr[cs][1], acc[mt][1], 0, 0, 0);
            }
        }
    }

    #pragma unroll
    for (int mt = 0; mt < 4; ++mt) {
        #pragma unroll
        for (int nt = 0; nt < 2; ++nt) {
            int pp = nt ? p1 : p0;
            #pragma unroll
            for (int r = 0; r < 4; ++r) {
                int oc = mt * 16 + lk * 4 + r;
                out[((size_t)b * OCH + oc) * HW + (size_t)yo * W + pp] = acc[mt][nt][r] + bias[oc];
            }
        }
    }
}

extern "C" void kernel_launch(void* const* d_in, const int* in_sizes, int n_in,
                              void* d_out, int out_size, void* d_ws, size_t ws_size,
                              hipStream_t stream) {
    const float* x     = (const float*)d_in[0];
    const float* w_off = (const float*)d_in[1];
    const float* w_def = (const float*)d_in[2];
    const float* b_def = (const float*)d_in[3];
    float* out = (float*)d_out;

    _Float16* wdf = (_Float16*)d_ws;                 // 36,864 f16
    _Float16* wof = wdf + 36864;                     // 18,432 f16

    prep_w_kernel<<<(36864 + 18432 + 255) / 256, 256, 0, stream>>>(w_def, w_off, wdf, wof);
    fused_deform_kernel<<<BATCH * H / 4, 1024, 0, stream>>>(
        x, (const f16x8*)wof, (const f16x8*)wdf, b_def, out);
}